// Round 2
// baseline (475.497 us; speedup 1.0000x reference)
//
#include <hip/hip_runtime.h>
#include <stdint.h>

typedef int v4i  __attribute__((ext_vector_type(4)));
typedef int v16i __attribute__((ext_vector_type(16)));

static constexpr int Mdim = 4096;
static constexpr int Kdim = 4096;   // IN
static constexpr int Ndim = 11008;  // OUT

#define BM 256
#define BN 256
#define BK 128
#define NT (Kdim / BK)  // 32 K-tiles

__device__ __forceinline__ void gload_lds16(const void* gp, void* lp) {
  __builtin_amdgcn_global_load_lds((const __attribute__((address_space(1))) void*)gp,
                                   (__attribute__((address_space(3))) void*)lp,
                                   16, 0, 0);
}

// ---------------- activation static quant + row sums ----------------
__global__ void k_quant(const float* __restrict__ x, const float* __restrict__ clampv,
                        signed char* __restrict__ qa, int* __restrict__ rowsum) {
  const int row = blockIdx.x;
  const int t = threadIdx.x;
  const float cv = clampv[0];
  const float a_scale = cv / 127.0f;
  const float4* xp = (const float4*)(x + (size_t)row * Kdim) + t * 4;
  int s = 0;
  int w[4];
#pragma unroll
  for (int i = 0; i < 4; ++i) {
    float4 f = xp[i];
    float q0 = fminf(fmaxf(rintf(fminf(fmaxf(f.x, -cv), cv) / a_scale), -127.f), 127.f);
    float q1 = fminf(fmaxf(rintf(fminf(fmaxf(f.y, -cv), cv) / a_scale), -127.f), 127.f);
    float q2 = fminf(fmaxf(rintf(fminf(fmaxf(f.z, -cv), cv) / a_scale), -127.f), 127.f);
    float q3 = fminf(fmaxf(rintf(fminf(fmaxf(f.w, -cv), cv) / a_scale), -127.f), 127.f);
    int i0 = (int)q0, i1 = (int)q1, i2 = (int)q2, i3 = (int)q3;
    s += i0 + i1 + i2 + i3;
    w[i] = (i0 & 255) | ((i1 & 255) << 8) | ((i2 & 255) << 16) | ((i3 & 255) << 24);
  }
  ((int4*)(qa + (size_t)row * Kdim))[t] = make_int4(w[0], w[1], w[2], w[3]);
#pragma unroll
  for (int off = 32; off > 0; off >>= 1) s += __shfl_down(s, off, 64);
  __shared__ int red[4];
  if ((t & 63) == 0) red[t >> 6] = s;
  __syncthreads();
  if (t == 0) rowsum[row] = red[0] + red[1] + red[2] + red[3];
}

// ---------------- int4 unpack: [N][K/2] int32 -> [N][K] int8 ----------------
__global__ void k_unpack(const int4* __restrict__ qw, uint2* __restrict__ wb) {
  const int idx = blockIdx.x * 256 + threadIdx.x;
  int4 q = qw[idx];
  uint2 r;
  r.x = (unsigned)(((q.x >> 4) & 15) | ((q.x & 15) << 8) |
                   (((q.y >> 4) & 15) << 16) | ((q.y & 15) << 24));
  r.y = (unsigned)(((q.z >> 4) & 15) | ((q.z & 15) << 8) |
                   (((q.w >> 4) & 15) << 16) | ((q.w & 15) << 24));
  wb[idx] = r;
}

// ---------------- int8 GEMM: 256x256 tile, 8 waves, 32x32x32 MFMA ----------------
// LDS[row][pos] holds global 16B-chunk (pos ^ (row&7)) of that row's 128B K-slab.
// Double-buffered K-tiles; ONE raw s_barrier + vmcnt(0) per K-tile (free wave drift).
__global__ __launch_bounds__(512, 2) void k_gemm(
    const signed char* __restrict__ A, const signed char* __restrict__ B,
    const float* __restrict__ scales, const int* __restrict__ qzeros,
    const float* __restrict__ bias, const float* __restrict__ clampv,
    const int* __restrict__ rowsum, float* __restrict__ out) {
  __shared__ signed char lds[131072];          // A: 2x32KB, B: 2x32KB
  signed char* As = lds;
  signed char* Bs = lds + 65536;

  const int t = threadIdx.x;
  const int lane = t & 63;
  const int wave = t >> 6;                      // 0..7 (2M x 4N)
  const int wm = (wave >> 2) * 128;
  const int wn = (wave & 3) * 64;

  // XCD-aware bijective swizzle: 688 blocks = 8 XCDs * 86
  const int bid = blockIdx.x;
  const int swz = (bid & 7) * 86 + (bid >> 3);
  const int mt = swz / 43;                      // consecutive swz share A panel
  const int nt = swz - mt * 43;
  const int m0 = mt * BM;
  const int n0 = nt * BN;

  // staging: thread t covers row srow (+i*64 per issue), LDS chunk t&7.
  // pre-swizzled global source chunk keeps LDS dest linear (gload_lds rule).
  const int srow = t >> 3;                      // 0..63
  const int sch = (t & 7) ^ (srow & 7);
  const signed char* gA = A + (size_t)(m0 + srow) * Kdim + sch * 16;
  const signed char* gB = B + (size_t)(n0 + srow) * Kdim + sch * 16;
  const int sdst = t * 16;

#define STAGE_A(buf, k0)                                               \
  {                                                                    \
    _Pragma("unroll") for (int i = 0; i < 4; ++i)                      \
        gload_lds16(gA + (size_t)(i * 64) * Kdim + (k0),               \
                    As + (buf) * 32768 + i * 8192 + sdst);             \
  }
#define STAGE_B(buf, k0)                                               \
  {                                                                    \
    _Pragma("unroll") for (int i = 0; i < 4; ++i)                      \
        gload_lds16(gB + (size_t)(i * 64) * Kdim + (k0),               \
                    Bs + (buf) * 32768 + i * 8192 + sdst);             \
  }

  // fragment addressing (32x32 MFMA): lane holds row (lane&31), 16B k-chunk
  // (ks*2 + lane>>5); stored chunk is XOR'd with row&7 == lane&7.
  const int col32 = lane & 31;
  const int q32 = lane >> 5;
  const int c7 = lane & 7;
  const int abase = (wm + col32) * BK;
  const int bbase = (wn + col32) * BK;
  int pos[4];
#pragma unroll
  for (int ks = 0; ks < 4; ++ks) pos[ks] = ((ks * 2 + q32) ^ c7) * 16;

  v16i acc[4][2] = {};
  v4i a[2][4], b[2][2];

#define LOADK(bank, ks_)                                                   \
  {                                                                        \
    _Pragma("unroll") for (int i = 0; i < 4; ++i)                          \
        a[bank][i] = *(const v4i*)(Ac + i * 4096 + abase + pos[ks_]);      \
    _Pragma("unroll") for (int j = 0; j < 2; ++j)                          \
        b[bank][j] = *(const v4i*)(Bc + j * 4096 + bbase + pos[ks_]);      \
  }

  // prologue: stage tile 0 into buffer 0, publish
  STAGE_A(0, 0);
  STAGE_B(0, 0);
  asm volatile("s_waitcnt vmcnt(0)" ::: "memory");
  __builtin_amdgcn_s_barrier();

  int cur = 0;
  for (int ti = 0; ti < NT; ++ti) {
    const int nk = (ti + 1) * BK;
    const bool pf = (ti + 1 < NT);
    const signed char* Ac = As + cur * 32768;
    const signed char* Bc = Bs + cur * 32768;

    // issue next-tile staging first (max time in flight before the drain)
    if (pf) {
      STAGE_A(cur ^ 1, nk);
      STAGE_B(cur ^ 1, nk);
    }

    // k-steps, 2-deep read-ahead pipeline, no intra-tile barriers
    LOADK(0, 0);
#pragma unroll
    for (int ks = 0; ks < 4; ++ks) {
      if (ks < 3) LOADK((ks + 1) & 1, ks + 1);
      __builtin_amdgcn_s_setprio(1);
#pragma unroll
      for (int i = 0; i < 4; ++i)
#pragma unroll
        for (int j = 0; j < 2; ++j)
          acc[i][j] = __builtin_amdgcn_mfma_i32_32x32x32_i8(a[ks & 1][i], b[ks & 1][j],
                                                            acc[i][j], 0, 0, 0);
      __builtin_amdgcn_s_setprio(0);
    }

    // all reads of buf 'cur' are drained (consumed by MFMAs above);
    // drain our stage loads, then flip.
    asm volatile("s_waitcnt vmcnt(0)" ::: "memory");
    __builtin_amdgcn_s_barrier();
    cur ^= 1;
  }
#undef STAGE_A
#undef STAGE_B
#undef LOADK

  // epilogue: out = a_scale*scale[n]*(acc - qz[n]*rowsum[m]) + bias[n]
  // 32x32 C/D layout: col = lane&31, row = (r&3) + 8*(r>>2) + 4*(lane>>5)
  const float a_scale = clampv[0] / 127.0f;
#pragma unroll
  for (int j = 0; j < 2; ++j) {
    const int n = n0 + wn + j * 32 + col32;
    const float sn = scales[n] * a_scale;
    const int zn = qzeros[n];
    const float bn = bias[n];
#pragma unroll
    for (int i = 0; i < 4; ++i) {
      const int mbase = m0 + wm + i * 32;
#pragma unroll
      for (int r = 0; r < 16; ++r) {
        const int row = (r & 3) + 8 * (r >> 2) + 4 * q32;
        const int m = mbase + row;
        const int iv = acc[i][j][r] - zn * rowsum[m];
        out[(size_t)m * Ndim + n] = (float)iv * sn + bn;
      }
    }
  }
}

extern "C" void kernel_launch(void* const* d_in, const int* in_sizes, int n_in,
                              void* d_out, int out_size, void* d_ws, size_t ws_size,
                              hipStream_t stream) {
  const float* x  = (const float*)d_in[0];
  const int* qw   = (const int*)d_in[1];
  const int* qz   = (const int*)d_in[2];
  const float* sc = (const float*)d_in[3];
  const float* bi = (const float*)d_in[4];
  const float* cv = (const float*)d_in[5];
  float* out = (float*)d_out;

  signed char* qa = (signed char*)d_ws;
  signed char* wb = qa + (size_t)Mdim * Kdim;
  int* rowsum = (int*)(wb + (size_t)Ndim * Kdim);

  k_quant<<<Mdim, 256, 0, stream>>>(x, cv, qa, rowsum);
  k_unpack<<<(Ndim * (Kdim / 2) / 4) / 256, 256, 0, stream>>>((const int4*)qw, (uint2*)wb);
  k_gemm<<<dim3((Mdim / BM) * (Ndim / BN)), 512, 0, stream>>>(qa, wb, sc, qz, bi, cv, rowsum, out);
}

// Round 3
// 462.413 us; speedup vs baseline: 1.0283x; 1.0283x over previous
//
#include <hip/hip_runtime.h>
#include <stdint.h>

typedef int v4i __attribute__((ext_vector_type(4)));

static constexpr int Mdim = 4096;
static constexpr int Kdim = 4096;   // IN
static constexpr int Ndim = 11008;  // OUT

#define BM 256
#define BN 256
#define BK 128
#define NT (Kdim / BK)  // 32 K-tiles

__device__ __forceinline__ void gload_lds16(const void* gp, void* lp) {
  __builtin_amdgcn_global_load_lds((const __attribute__((address_space(1))) void*)gp,
                                   (__attribute__((address_space(3))) void*)lp,
                                   16, 0, 0);
}

// ---------------- activation static quant + row sums ----------------
__global__ void k_quant(const float* __restrict__ x, const float* __restrict__ clampv,
                        signed char* __restrict__ qa, int* __restrict__ rowsum) {
  const int row = blockIdx.x;
  const int t = threadIdx.x;
  const float cv = clampv[0];
  const float a_scale = cv / 127.0f;
  const float4* xp = (const float4*)(x + (size_t)row * Kdim) + t * 4;
  int s = 0;
  int w[4];
#pragma unroll
  for (int i = 0; i < 4; ++i) {
    float4 f = xp[i];
    float q0 = fminf(fmaxf(rintf(fminf(fmaxf(f.x, -cv), cv) / a_scale), -127.f), 127.f);
    float q1 = fminf(fmaxf(rintf(fminf(fmaxf(f.y, -cv), cv) / a_scale), -127.f), 127.f);
    float q2 = fminf(fmaxf(rintf(fminf(fmaxf(f.z, -cv), cv) / a_scale), -127.f), 127.f);
    float q3 = fminf(fmaxf(rintf(fminf(fmaxf(f.w, -cv), cv) / a_scale), -127.f), 127.f);
    int i0 = (int)q0, i1 = (int)q1, i2 = (int)q2, i3 = (int)q3;
    s += i0 + i1 + i2 + i3;
    w[i] = (i0 & 255) | ((i1 & 255) << 8) | ((i2 & 255) << 16) | ((i3 & 255) << 24);
  }
  ((int4*)(qa + (size_t)row * Kdim))[t] = make_int4(w[0], w[1], w[2], w[3]);
#pragma unroll
  for (int off = 32; off > 0; off >>= 1) s += __shfl_down(s, off, 64);
  __shared__ int red[4];
  if ((t & 63) == 0) red[t >> 6] = s;
  __syncthreads();
  if (t == 0) rowsum[row] = red[0] + red[1] + red[2] + red[3];
}

// ---------------- int4 unpack: [N][K/2] int32 -> [N][K] int8 ----------------
__global__ void k_unpack(const int4* __restrict__ qw, uint2* __restrict__ wb) {
  const int idx = blockIdx.x * 256 + threadIdx.x;
  int4 q = qw[idx];
  uint2 r;
  r.x = (unsigned)(((q.x >> 4) & 15) | ((q.x & 15) << 8) |
                   (((q.y >> 4) & 15) << 16) | ((q.y & 15) << 24));
  r.y = (unsigned)(((q.z >> 4) & 15) | ((q.z & 15) << 8) |
                   (((q.w >> 4) & 15) << 16) | ((q.w & 15) << 24));
  wb[idx] = r;
}

// ---------------- int8 GEMM: 256x256 tile, 8 waves, 16x16x64 MFMA ----------------
// LDS[row][pos] holds global 16B-chunk (pos ^ (row&7)) of that row's 128B K-slab
// (conflict-free for 16-row fragment reads; verified 0 conflicts in R1).
// Double-buffered K-tiles; ONE raw s_barrier + vmcnt(0) per K-tile (free wave drift).
// Safety: every ds_read of buf[cur] is consumed by an MFMA before the barrier, so
// lgkm waits force read completion before any wave can flip and overwrite.
__global__ __launch_bounds__(512, 2) void k_gemm(
    const signed char* __restrict__ A, const signed char* __restrict__ B,
    const float* __restrict__ scales, const int* __restrict__ qzeros,
    const float* __restrict__ bias, const float* __restrict__ clampv,
    const int* __restrict__ rowsum, float* __restrict__ out) {
  __shared__ signed char lds[131072];          // A: 2x32KB, B: 2x32KB
  signed char* As = lds;
  signed char* Bs = lds + 65536;

  const int t = threadIdx.x;
  const int lane = t & 63;
  const int wave = t >> 6;                      // 0..7 (2M x 4N)
  const int wm = (wave >> 2) * 128;
  const int wn = (wave & 3) * 64;

  // XCD-aware bijective swizzle: 688 blocks = 8 XCDs * 86
  const int bid = blockIdx.x;
  const int swz = (bid & 7) * 86 + (bid >> 3);
  const int mt = swz / 43;                      // consecutive swz share A panel
  const int nt = swz - mt * 43;
  const int m0 = mt * BM;
  const int n0 = nt * BN;

  // staging: thread t covers row srow (+i*64 per issue), LDS chunk t&7.
  // pre-swizzled global source chunk keeps LDS dest linear (gload_lds rule).
  const int srow = t >> 3;                      // 0..63
  const int sch = (t & 7) ^ (srow & 7);
  const signed char* gA = A + (size_t)(m0 + srow) * Kdim + sch * 16;
  const signed char* gB = B + (size_t)(n0 + srow) * Kdim + sch * 16;
  const int sdst = t * 16;

#define STAGE_A(buf, k0)                                               \
  {                                                                    \
    _Pragma("unroll") for (int i = 0; i < 4; ++i)                      \
        gload_lds16(gA + (size_t)(i * 64) * Kdim + (k0),               \
                    As + (buf) * 32768 + i * 8192 + sdst);             \
  }
#define STAGE_B(buf, k0)                                               \
  {                                                                    \
    _Pragma("unroll") for (int i = 0; i < 4; ++i)                      \
        gload_lds16(gB + (size_t)(i * 64) * Kdim + (k0),               \
                    Bs + (buf) * 32768 + i * 8192 + sdst);             \
  }

  // fragment addressing (16x16 MFMA): col = lane&15, 16B chunk (ks*4 + lane>>4),
  // stored chunk XOR'd with row&7 == col&7 (wm, i*16 are multiples of 8).
  const int col = lane & 15;
  const int q16 = lane >> 4;
  const int c7 = col & 7;
  int aoff[2], boff[2];
#pragma unroll
  for (int ks = 0; ks < 2; ++ks) {
    const int pos = ((ks * 4 + q16) ^ c7) * 16;
    aoff[ks] = (wm + col) * BK + pos;
    boff[ks] = (wn + col) * BK + pos;
  }

  v4i acc[8][4] = {};
  v4i a[2][8], b[2][4];

#define LOADK(bank, ks_)                                                    \
  {                                                                         \
    _Pragma("unroll") for (int i = 0; i < 8; ++i)                           \
        a[bank][i] = *(const v4i*)(Ac + i * 2048 + aoff[ks_]);              \
    _Pragma("unroll") for (int j = 0; j < 4; ++j)                           \
        b[bank][j] = *(const v4i*)(Bc + j * 2048 + boff[ks_]);              \
  }
#define MFMAK(bank)                                                         \
  {                                                                         \
    __builtin_amdgcn_s_setprio(1);                                          \
    _Pragma("unroll") for (int i = 0; i < 8; ++i)                           \
        _Pragma("unroll") for (int j = 0; j < 4; ++j)                       \
            acc[i][j] = __builtin_amdgcn_mfma_i32_16x16x64_i8(              \
                a[bank][i], b[bank][j], acc[i][j], 0, 0, 0);                \
    __builtin_amdgcn_s_setprio(0);                                          \
  }

  // prologue: stage tile 0 into buffer 0, publish
  STAGE_A(0, 0);
  STAGE_B(0, 0);
  asm volatile("s_waitcnt vmcnt(0)" ::: "memory");
  __builtin_amdgcn_s_barrier();

  int cur = 0;
  for (int ti = 0; ti < NT - 1; ++ti) {
    const int nk = (ti + 1) * BK;
    const signed char* Ac = As + cur * 32768;
    const signed char* Bc = Bs + cur * 32768;

    // issue next-tile staging first (max time in flight before the drain)
    STAGE_A(cur ^ 1, nk);
    STAGE_B(cur ^ 1, nk);

    // 2 k-steps; reads of ks1 overlap MFMAs of ks0 (compiler-counted lgkm waits)
    LOADK(0, 0);
    LOADK(1, 1);
    MFMAK(0);
    MFMAK(1);

    // drain our stage loads (issued ~2600 cy ago), then flip
    asm volatile("s_waitcnt vmcnt(0)" ::: "memory");
    __builtin_amdgcn_s_barrier();
    cur ^= 1;
  }
  // last tile: no prefetch, no barrier needed after
  {
    const signed char* Ac = As + cur * 32768;
    const signed char* Bc = Bs + cur * 32768;
    LOADK(0, 0);
    LOADK(1, 1);
    MFMAK(0);
    MFMAK(1);
  }
#undef STAGE_A
#undef STAGE_B
#undef LOADK
#undef MFMAK

  // epilogue: out = a_scale*scale[n]*(acc - qz[n]*rowsum[m]) + bias[n]
  const float a_scale = clampv[0] / 127.0f;
  const int rq = q16 * 4;
  int rs[8][4];
#pragma unroll
  for (int i = 0; i < 8; ++i)
#pragma unroll
    for (int r = 0; r < 4; ++r)
      rs[i][r] = rowsum[m0 + wm + i * 16 + rq + r];
#pragma unroll
  for (int j = 0; j < 4; ++j) {
    const int n = n0 + wn + j * 16 + col;
    const float sn = scales[n] * a_scale;
    const int zn = qzeros[n];
    const float bn = bias[n];
#pragma unroll
    for (int i = 0; i < 8; ++i) {
      const int mb = m0 + wm + i * 16 + rq;
#pragma unroll
      for (int r = 0; r < 4; ++r) {
        const int iv = acc[i][j][r] - zn * rs[i][r];
        out[(size_t)(mb + r) * Ndim + n] = (float)iv * sn + bn;
      }
    }
  }
}

extern "C" void kernel_launch(void* const* d_in, const int* in_sizes, int n_in,
                              void* d_out, int out_size, void* d_ws, size_t ws_size,
                              hipStream_t stream) {
  const float* x  = (const float*)d_in[0];
  const int* qw   = (const int*)d_in[1];
  const int* qz   = (const int*)d_in[2];
  const float* sc = (const float*)d_in[3];
  const float* bi = (const float*)d_in[4];
  const float* cv = (const float*)d_in[5];
  float* out = (float*)d_out;

  signed char* qa = (signed char*)d_ws;
  signed char* wb = qa + (size_t)Mdim * Kdim;
  int* rowsum = (int*)(wb + (size_t)Ndim * Kdim);

  k_quant<<<Mdim, 256, 0, stream>>>(x, cv, qa, rowsum);
  k_unpack<<<(Ndim * (Kdim / 2) / 4) / 256, 256, 0, stream>>>((const int4*)qw, (uint2*)wb);
  k_gemm<<<dim3((Mdim / BM) * (Ndim / BN)), 512, 0, stream>>>(qa, wb, sc, qz, bi, cv, rowsum, out);
}